// Round 5
// baseline (364.000 us; speedup 1.0000x reference)
//
#include <hip/hip_runtime.h>
#include <stdint.h>

#define TOKENS 8192
#define EDIM 512
#define HNUM 8
#define RNUM 16
#define DDIM 64
#define KDIM 512

typedef short v8s __attribute__((ext_vector_type(8)));
typedef float v4f __attribute__((ext_vector_type(4)));

__device__ inline float b2f(unsigned short u) {
    union { unsigned int i; float f; } c; c.i = ((unsigned int)u) << 16; return c.f;
}
__device__ inline unsigned short f2b(float f) {
    union { float f; unsigned int i; } c; c.f = f;
    unsigned int i = c.i + 0x7fffu + ((c.i >> 16) & 1u);
    return (unsigned short)(i >> 16);
}

// async global->LDS, 16B per lane; LDS dest = wave-uniform base + lane*16
#define GLD16(dst, src) \
    __builtin_amdgcn_global_load_lds((__attribute__((address_space(1))) void*)(src), \
                                     (__attribute__((address_space(3))) void*)(dst), 16, 0, 0)

// ---- fp32 -> bf16 convert, 3 segments (value, Wv, Wo) ----
__global__ __launch_bounds__(256)
void cvt3(const float* __restrict__ s0, const float* __restrict__ s1,
          const float* __restrict__ s2,
          unsigned short* __restrict__ d0, unsigned short* __restrict__ d1,
          unsigned short* __restrict__ d2,
          int n0, int n1, int n2)
{
    const float* s; unsigned short* d; int n;
    switch (blockIdx.y) {
        case 0: s = s0; d = d0; n = n0; break;
        case 1: s = s1; d = d1; n = n1; break;
        default: s = s2; d = d2; n = n2; break;
    }
    size_t base = (size_t)blockIdx.x * 2048 + (size_t)threadIdx.x * 8;
    if (base >= (size_t)n) return;
    const float4* sp = (const float4*)(s + base);
    float4 f0 = sp[0], f1 = sp[1];
    v8s o;
    o[0] = (short)f2b(f0.x); o[1] = (short)f2b(f0.y);
    o[2] = (short)f2b(f0.z); o[3] = (short)f2b(f0.w);
    o[4] = (short)f2b(f1.x); o[5] = (short)f2b(f1.y);
    o[6] = (short)f2b(f1.z); o[7] = (short)f2b(f1.w);
    *(v8s*)(d + base) = o;
}

// ---- fused Q-projection + fuzzy rules + softmax ----
// grid (TOKENS/64, HNUM). m-tile = 64 tokens, n-tile = head h's 64 dims.
// GEMM stages fp32 inputs with inline bf16 convert (padded LDS, conflict-free),
// q tile stays in LDS, rules+softmax computed in-block, only attn written.
#define QST 40   // staging row stride (shorts): 80 B, 16B-aligned, conflict-free
#define QSF 68   // q tile row stride (floats)
__global__ __launch_bounds__(256, 4)
void qrules(const float* __restrict__ query,
            const float* __restrict__ Wq,
            const float* __restrict__ bq,
            const float* __restrict__ rk,
            const float* __restrict__ rw,
            float* __restrict__ attn)
{
    __shared__ unsigned short As[64 * QST];
    __shared__ unsigned short Bs[64 * QST];
    __shared__ float qs[64 * QSF];
    __shared__ float rkl[16 * QSF];
    __shared__ float iwl[16 * QSF];

    const int tid  = threadIdx.x;
    const int w    = tid >> 6;
    const int lane = tid & 63;
    const int quad = lane >> 4;
    const int l16  = lane & 15;
    const int wm   = w >> 1, wn = w & 1;
    const int t0   = blockIdx.x * 64;   // token base
    const int h    = blockIdx.y;
    const int n0   = h * 64;            // Wq row base

    // stage rules for this head (once)
    {
        int r = tid >> 4, d = (tid & 15) * 4;
        float4 kv = *(const float4*)&rk[h * (RNUM * DDIM) + r * DDIM + d];
        float4 wv = *(const float4*)&rw[h * (RNUM * DDIM) + r * DDIM + d];
        *(float4*)&rkl[r * QSF + d] = kv;
        float4 iw;
        iw.x = 1.0f / (wv.x * wv.x); iw.y = 1.0f / (wv.y * wv.y);
        iw.z = 1.0f / (wv.z * wv.z); iw.w = 1.0f / (wv.w * wv.w);
        *(float4*)&iwl[r * QSF + d] = iw;
    }

    v4f acc[2][2];
#pragma unroll
    for (int i = 0; i < 2; ++i)
#pragma unroll
        for (int j = 0; j < 2; ++j)
            acc[i][j] = (v4f){0.f, 0.f, 0.f, 0.f};

    const int srow = tid >> 2;          // staging: thread -> (row, 8-elem chunk)
    const int scc  = tid & 3;
    for (int kt = 0; kt < KDIM / 32; ++kt) {
        {
            const float* sa = query + (size_t)(t0 + srow) * KDIM + kt * 32 + scc * 8;
            float4 a0 = *(const float4*)sa, a1 = *(const float4*)(sa + 4);
            v8s oa;
            oa[0] = (short)f2b(a0.x); oa[1] = (short)f2b(a0.y);
            oa[2] = (short)f2b(a0.z); oa[3] = (short)f2b(a0.w);
            oa[4] = (short)f2b(a1.x); oa[5] = (short)f2b(a1.y);
            oa[6] = (short)f2b(a1.z); oa[7] = (short)f2b(a1.w);
            const float* sb = Wq + (size_t)(n0 + srow) * KDIM + kt * 32 + scc * 8;
            float4 b0 = *(const float4*)sb, b1 = *(const float4*)(sb + 4);
            v8s ob;
            ob[0] = (short)f2b(b0.x); ob[1] = (short)f2b(b0.y);
            ob[2] = (short)f2b(b0.z); ob[3] = (short)f2b(b0.w);
            ob[4] = (short)f2b(b1.x); ob[5] = (short)f2b(b1.y);
            ob[6] = (short)f2b(b1.z); ob[7] = (short)f2b(b1.w);
            __syncthreads();   // protect LDS from previous iter's readers
            *(v8s*)&As[srow * QST + scc * 8] = oa;
            *(v8s*)&Bs[srow * QST + scc * 8] = ob;
        }
        __syncthreads();

        v8s af[2], bf[2];
#pragma unroll
        for (int mt = 0; mt < 2; ++mt)
            af[mt] = *(const v8s*)&As[(wm * 32 + mt * 16 + l16) * QST + quad * 8];
#pragma unroll
        for (int nt = 0; nt < 2; ++nt)
            bf[nt] = *(const v8s*)&Bs[(wn * 32 + nt * 16 + l16) * QST + quad * 8];
#pragma unroll
        for (int mt = 0; mt < 2; ++mt)
#pragma unroll
            for (int nt = 0; nt < 2; ++nt)
                acc[mt][nt] = __builtin_amdgcn_mfma_f32_16x16x32_bf16(af[mt], bf[nt], acc[mt][nt], 0, 0, 0);
    }
    __syncthreads();

    // epilogue: q = (C + bq)*0.125 -> LDS q tile
#pragma unroll
    for (int mt = 0; mt < 2; ++mt)
#pragma unroll
        for (int nt = 0; nt < 2; ++nt) {
            int col = wn * 32 + nt * 16 + l16;       // local d
            float bb = bq[n0 + col];
#pragma unroll
            for (int rg = 0; rg < 4; ++rg) {
                int row = wm * 32 + mt * 16 + quad * 4 + rg;   // local token
                qs[row * QSF + col] = (acc[mt][nt][rg] + bb) * 0.125f;
            }
        }
    __syncthreads();

    // rules + softmax: 4 passes x (16 tokens x 16 rules)
    const int grp = tid >> 4;   // token-in-pass (consecutive 16 lanes share it)
    const int r   = tid & 15;   // rule
    const float* krow = &rkl[r * QSF];
    const float* wrow = &iwl[r * QSF];
#pragma unroll
    for (int p = 0; p < 4; ++p) {
        int tok = p * 16 + grp;
        const float* qrow = &qs[tok * QSF];
        float z = 0.f;
#pragma unroll
        for (int d4 = 0; d4 < 16; ++d4) {
            float4 qv = *(const float4*)&qrow[d4 * 4];
            float4 kv = *(const float4*)&krow[d4 * 4];
            float4 wv = *(const float4*)&wrow[d4 * 4];
            float a0 = qv.x - kv.x; z += a0 * a0 * wv.x;
            float a1 = qv.y - kv.y; z += a1 * a1 * wv.y;
            float a2 = qv.z - kv.z; z += a2 * a2 * wv.z;
            float a3 = qv.w - kv.w; z += a3 * a3 * wv.w;
        }
        z *= (-0.5f / 64.f);
        float mx = z;
#pragma unroll
        for (int s = 1; s < 16; s <<= 1) mx = fmaxf(mx, __shfl_xor(mx, s));
        float e = __expf(z - mx);
        float sum = e;
#pragma unroll
        for (int s = 1; s < 16; s <<= 1) sum += __shfl_xor(sum, s);
        attn[(size_t)(t0 + tok) * (HNUM * RNUM) + h * RNUM + r] = e / sum;
    }
}

// ---- V-GEMM: 128x128 tiles, BK=64, XOR-swizzled LDS (conflict-free) ----
// TRANSPOSED: m = Wv rows (h*1024+d*16+r), n = tokens. Rule contraction over
// r = quad*4+reg, LDS-staged coalesced store of scrambled out1.
__global__ __launch_bounds__(256, 2)
void gemm_v(const unsigned short* __restrict__ A,
            const unsigned short* __restrict__ B,
            const float* __restrict__ bias,
            unsigned short* __restrict__ outH,
            const float* __restrict__ attn)
{
    __shared__ unsigned short As[128 * 64];   // 16 KB, k-chunk cc stored at cc^(row&7)
    __shared__ unsigned short Bs[128 * 64];
    __shared__ unsigned short Os[128 * 8];

    const int tid  = threadIdx.x;
    const int w    = tid >> 6;
    const int lane = tid & 63;
    const int quad = lane >> 4;
    const int l16  = lane & 15;
    const int wm   = w >> 1, wn = w & 1;
    const int m0   = blockIdx.x * 128;
    const int n0   = blockIdx.y * 128;

    v4f acc[4][4];
#pragma unroll
    for (int i = 0; i < 4; ++i)
#pragma unroll
        for (int j = 0; j < 4; ++j)
            acc[i][j] = (v4f){0.f, 0.f, 0.f, 0.f};

    for (int kt = 0; kt < KDIM / 64; ++kt) {
        // stage 128x64 tiles: 1024 chunks of 16B each; 4 GLD16 issues per operand
#pragma unroll
        for (int p = 0; p < 4; ++p) {
            int cb  = w * 256 + p * 64;       // wave-uniform chunk base
            int c   = cb + lane;
            int row = c >> 3;
            int cc  = (c & 7) ^ (row & 7);    // XOR swizzle: source k-chunk
            const unsigned short* sa = A + (size_t)(m0 + row) * KDIM + kt * 64 + cc * 8;
            GLD16(&As[cb * 8], sa);
            const unsigned short* sb = B + (size_t)(n0 + row) * KDIM + kt * 64 + cc * 8;
            GLD16(&Bs[cb * 8], sb);
        }
        __syncthreads();

#pragma unroll
        for (int kk = 0; kk < 2; ++kk) {
            v8s af[4], bf[4];
#pragma unroll
            for (int mt = 0; mt < 4; ++mt) {
                int swz = (kk * 4 + quad) ^ (l16 & 7);
                af[mt] = *(const v8s*)&As[(wm * 64 + mt * 16 + l16) * 64 + swz * 8];
            }
#pragma unroll
            for (int nt = 0; nt < 4; ++nt) {
                int swz = (kk * 4 + quad) ^ (l16 & 7);
                bf[nt] = *(const v8s*)&Bs[(wn * 64 + nt * 16 + l16) * 64 + swz * 8];
            }
#pragma unroll
            for (int mt = 0; mt < 4; ++mt)
#pragma unroll
                for (int nt = 0; nt < 4; ++nt)
                    acc[mt][nt] = __builtin_amdgcn_mfma_f32_16x16x32_bf16(af[mt], bf[nt], acc[mt][nt], 0, 0, 0);
        }
        __syncthreads();
    }

    const int h  = m0 >> 10;          // head (uniform per block)
    const int d0 = (m0 >> 4) & 63;    // first of this block's 8 d values
    float4 bias4[4];
#pragma unroll
    for (int mt = 0; mt < 4; ++mt)
        bias4[mt] = *(const float4*)&bias[m0 + wm * 64 + mt * 16 + quad * 4];
#pragma unroll
    for (int nt = 0; nt < 4; ++nt) {
        int token = n0 + wn * 64 + nt * 16 + l16;
        float4 av = *(const float4*)&attn[(size_t)token * (HNUM * RNUM) + h * RNUM + quad * 4];
#pragma unroll
        for (int mt = 0; mt < 4; ++mt) {
            v4f a = acc[mt][nt];
            float val = (a[0] + bias4[mt].x) * av.x
                      + (a[1] + bias4[mt].y) * av.y
                      + (a[2] + bias4[mt].z) * av.z
                      + (a[3] + bias4[mt].w) * av.w;
            val += __shfl_xor(val, 16);
            val += __shfl_xor(val, 32);
            if (quad == 0)
                Os[(wn * 64 + nt * 16 + l16) * 8 + (wm * 4 + mt)] = f2b(val * 0.125f);
        }
    }
    __syncthreads();
    if (tid < 128) {
        int sg = n0 + tid;            // global token
        int g  = (sg >> 11) * 2048 + h * 256 + ((sg & 2047) >> 3);
        int j  = (sg & 7) * 64 + d0;
        *(v8s*)&outH[(size_t)g * EDIM + j] = *(const v8s*)&Os[tid * 8];
    }
}

// ---- O-projection: 64x64 tiles, outF = C + bias[n] ----
__global__ __launch_bounds__(256, 4)
void gemm_o(const unsigned short* __restrict__ A,
            const unsigned short* __restrict__ B,
            const float* __restrict__ bias,
            float* __restrict__ outF)
{
    __shared__ unsigned short As[64 * 32];
    __shared__ unsigned short Bs[64 * 32];

    const int tid  = threadIdx.x;
    const int w    = tid >> 6;
    const int lane = tid & 63;
    const int quad = lane >> 4;
    const int l16  = lane & 15;
    const int wm   = w >> 1, wn = w & 1;
    const int m0   = blockIdx.x * 64;
    const int n0   = blockIdx.y * 64;

    v4f acc[2][2];
#pragma unroll
    for (int i = 0; i < 2; ++i)
#pragma unroll
        for (int j = 0; j < 2; ++j)
            acc[i][j] = (v4f){0.f, 0.f, 0.f, 0.f};

    for (int kt = 0; kt < KDIM / 32; ++kt) {
        int c = w * 64 + lane;
        const unsigned short* sa = A + (size_t)(m0 + (c >> 2)) * KDIM + kt * 32 + (c & 3) * 8;
        GLD16(&As[w * 512], sa);
        const unsigned short* sb = B + (size_t)(n0 + (c >> 2)) * KDIM + kt * 32 + (c & 3) * 8;
        GLD16(&Bs[w * 512], sb);
        __syncthreads();

        v8s af[2], bf[2];
#pragma unroll
        for (int mt = 0; mt < 2; ++mt)
            af[mt] = *(const v8s*)&As[(wm * 32 + mt * 16 + l16) * 32 + quad * 8];
#pragma unroll
        for (int nt = 0; nt < 2; ++nt)
            bf[nt] = *(const v8s*)&Bs[(wn * 32 + nt * 16 + l16) * 32 + quad * 8];
#pragma unroll
        for (int mt = 0; mt < 2; ++mt)
#pragma unroll
            for (int nt = 0; nt < 2; ++nt)
                acc[mt][nt] = __builtin_amdgcn_mfma_f32_16x16x32_bf16(af[mt], bf[nt], acc[mt][nt], 0, 0, 0);
        __syncthreads();
    }

#pragma unroll
    for (int mt = 0; mt < 2; ++mt)
#pragma unroll
        for (int nt = 0; nt < 2; ++nt) {
            int col = n0 + wn * 32 + nt * 16 + l16;
            float bb = bias[col];
#pragma unroll
            for (int rg = 0; rg < 4; ++rg) {
                int row = m0 + wm * 32 + mt * 16 + quad * 4 + rg;
                outF[(size_t)row * EDIM + col] = acc[mt][nt][rg] + bb;
            }
        }
}

extern "C" void kernel_launch(void* const* d_in, const int* in_sizes, int n_in,
                              void* d_out, int out_size, void* d_ws, size_t ws_size,
                              hipStream_t stream) {
    const float* query = (const float*)d_in[0];
    // d_in[1] = key (unused by the reference)
    const float* value = (const float*)d_in[2];
    const float* Wq = (const float*)d_in[3];
    const float* bq = (const float*)d_in[4];
    const float* Wv = (const float*)d_in[5];
    const float* bv = (const float*)d_in[6];
    const float* Wo = (const float*)d_in[7];
    const float* bo = (const float*)d_in[8];
    const float* rk = (const float*)d_in[9];
    const float* rw = (const float*)d_in[10];

    char* ws = (char*)d_ws;
    unsigned short* vbf  = (unsigned short*)(ws);                       //  8 MiB: value bf16
    unsigned short* Wvb  = (unsigned short*)(ws + (size_t)( 8 << 20));  //  8 MiB: Wv bf16
    unsigned short* Wob  = (unsigned short*)(ws + (size_t)(16 << 20));  // 0.5 MiB: Wo bf16
    unsigned short* out1 = (unsigned short*)(ws + (size_t)(17 << 20));  //  8 MiB: scrambled bf16
    float* attn          = (float*)(ws + (size_t)(25 << 20));           //  4 MiB: attn fp32

    dim3 blk(256);
    // 0) fp32 -> bf16 conversions (value, Wv, Wo)
    cvt3<<<dim3(2048, 3), blk, 0, stream>>>(value, Wv, Wo, vbf, Wvb, Wob,
                                            TOKENS * EDIM, EDIM * RNUM * EDIM, EDIM * EDIM);
    // 1) fused Q-projection + rules + softmax -> attn
    qrules<<<dim3(TOKENS / 64, HNUM), blk, 0, stream>>>(query, Wq, bq, rk, rw, attn);
    // 2) transposed V-GEMM (BK=64, swizzled) + rule contraction -> scrambled out1
    gemm_v<<<dim3((EDIM * RNUM) / 128, TOKENS / 128), blk, 0, stream>>>(Wvb, vbf, bv, out1, attn);
    // 3) final projection -> d_out (fp32)
    gemm_o<<<dim3(TOKENS / 64, EDIM / 64), blk, 0, stream>>>(out1, Wob, bo, (float*)d_out);
}

// Round 6
// 237.379 us; speedup vs baseline: 1.5334x; 1.5334x over previous
//
#include <hip/hip_runtime.h>
#include <stdint.h>

#define TOKENS 8192
#define EDIM 512
#define HNUM 8
#define RNUM 16
#define DDIM 64
#define KDIM 512

typedef short v8s __attribute__((ext_vector_type(8)));
typedef float v4f __attribute__((ext_vector_type(4)));

__device__ inline float b2f(unsigned short u) {
    union { unsigned int i; float f; } c; c.i = ((unsigned int)u) << 16; return c.f;
}
__device__ inline unsigned short f2b(float f) {
    union { float f; unsigned int i; } c; c.f = f;
    unsigned int i = c.i + 0x7fffu + ((c.i >> 16) & 1u);
    return (unsigned short)(i >> 16);
}

// async global->LDS, 16B per lane; LDS dest = wave-uniform base + lane*16
#define GLD16(dst, src) \
    __builtin_amdgcn_global_load_lds((__attribute__((address_space(1))) void*)(src), \
                                     (__attribute__((address_space(3))) void*)(dst), 16, 0, 0)

// ---- fp32 -> bf16 convert, 5 segments in one launch (blockIdx.y picks) ----
__global__ __launch_bounds__(256)
void cvt5(const float* __restrict__ s0, const float* __restrict__ s1,
          const float* __restrict__ s2, const float* __restrict__ s3,
          const float* __restrict__ s4,
          unsigned short* __restrict__ d0, unsigned short* __restrict__ d1,
          unsigned short* __restrict__ d2, unsigned short* __restrict__ d3,
          unsigned short* __restrict__ d4,
          int n0, int n1, int n2, int n3, int n4)
{
    const float* s; unsigned short* d; int n;
    switch (blockIdx.y) {
        case 0: s = s0; d = d0; n = n0; break;
        case 1: s = s1; d = d1; n = n1; break;
        case 2: s = s2; d = d2; n = n2; break;
        case 3: s = s3; d = d3; n = n3; break;
        default: s = s4; d = d4; n = n4; break;
    }
    size_t base = (size_t)blockIdx.x * 2048 + (size_t)threadIdx.x * 8;
    if (base >= (size_t)n) return;
    const float4* sp = (const float4*)(s + base);
    float4 f0 = sp[0], f1 = sp[1];
    v8s o;
    o[0] = (short)f2b(f0.x); o[1] = (short)f2b(f0.y);
    o[2] = (short)f2b(f0.z); o[3] = (short)f2b(f0.w);
    o[4] = (short)f2b(f1.x); o[5] = (short)f2b(f1.y);
    o[6] = (short)f2b(f1.z); o[7] = (short)f2b(f1.w);
    *(v8s*)(d + base) = o;
}

// ---- small-GEMM path: 64x64 tiles, 1024 blocks -> 4 blocks/CU ----
// XOR-swizzled LDS: slot s of row R holds source k-chunk s ^ ((R>>1)&3).
// MODE 0: outH = bf16((C + bias[n]) * 0.125)   (Q projection)
// MODE 2: outF = C + bias[n]                   (O projection)
template <int MODE>
__global__ __launch_bounds__(256, 4)
void gemm64(const unsigned short* __restrict__ A,
            const unsigned short* __restrict__ B,
            const float* __restrict__ bias,
            float* __restrict__ outF,
            unsigned short* __restrict__ outH)
{
    __shared__ unsigned short As[64 * 32];
    __shared__ unsigned short Bs[64 * 32];

    const int tid  = threadIdx.x;
    const int w    = tid >> 6;
    const int lane = tid & 63;
    const int quad = lane >> 4;
    const int l16  = lane & 15;
    const int wm   = w >> 1, wn = w & 1;
    const int m0   = blockIdx.x * 64;
    const int n0   = blockIdx.y * 64;
    const int swz  = quad ^ ((l16 >> 1) & 3);   // fragment slot (bank-conflict-free)

    v4f acc[2][2];
#pragma unroll
    for (int i = 0; i < 2; ++i)
#pragma unroll
        for (int j = 0; j < 2; ++j)
            acc[i][j] = (v4f){0.f, 0.f, 0.f, 0.f};

    for (int kt = 0; kt < KDIM / 32; ++kt) {
        int c   = w * 64 + lane;
        int row = c >> 2;
        int cc  = (c & 3) ^ ((c >> 3) & 3);     // source k-chunk for this slot
        const unsigned short* sa = A + (size_t)(m0 + row) * KDIM + kt * 32 + cc * 8;
        GLD16(&As[w * 512], sa);
        const unsigned short* sb = B + (size_t)(n0 + row) * KDIM + kt * 32 + cc * 8;
        GLD16(&Bs[w * 512], sb);
        __syncthreads();

        v8s af[2], bf[2];
#pragma unroll
        for (int mt = 0; mt < 2; ++mt)
            af[mt] = *(const v8s*)&As[(wm * 32 + mt * 16 + l16) * 32 + swz * 8];
#pragma unroll
        for (int nt = 0; nt < 2; ++nt)
            bf[nt] = *(const v8s*)&Bs[(wn * 32 + nt * 16 + l16) * 32 + swz * 8];
#pragma unroll
        for (int mt = 0; mt < 2; ++mt)
#pragma unroll
            for (int nt = 0; nt < 2; ++nt)
                acc[mt][nt] = __builtin_amdgcn_mfma_f32_16x16x32_bf16(af[mt], bf[nt], acc[mt][nt], 0, 0, 0);
        __syncthreads();
    }

#pragma unroll
    for (int mt = 0; mt < 2; ++mt)
#pragma unroll
        for (int nt = 0; nt < 2; ++nt) {
            int col = n0 + wn * 32 + nt * 16 + l16;
            float bb = bias[col];
#pragma unroll
            for (int rg = 0; rg < 4; ++rg) {
                int row = m0 + wm * 32 + mt * 16 + quad * 4 + rg;
                float v = acc[mt][nt][rg] + bb;
                if (MODE == 0) outH[(size_t)row * EDIM + col] = f2b(v * 0.125f);
                else           outF[(size_t)row * EDIM + col] = v;
            }
        }
}

// ---- V-GEMM: 128x128 tiles, BK=32, XOR-swizzled LDS, TRANSPOSED ----
// m = Wv rows (h*1024+d*16+r), n = tokens. Rule contraction over r = quad*4+reg
// (in-register + 2 shfl), LDS-staged coalesced store of scrambled out1.
__global__ __launch_bounds__(256, 2)
void gemm_v(const unsigned short* __restrict__ A,
            const unsigned short* __restrict__ B,
            const float* __restrict__ bias,
            unsigned short* __restrict__ outH,
            const float* __restrict__ attn)
{
    __shared__ unsigned short As[128 * 32];
    __shared__ unsigned short Bs[128 * 32];
    __shared__ unsigned short Os[128 * 8];

    const int tid  = threadIdx.x;
    const int w    = tid >> 6;
    const int lane = tid & 63;
    const int quad = lane >> 4;
    const int l16  = lane & 15;
    const int wm   = w >> 1, wn = w & 1;
    const int m0   = blockIdx.x * 128;
    const int n0   = blockIdx.y * 128;
    const int swz  = quad ^ ((l16 >> 1) & 3);

    v4f acc[4][4];
#pragma unroll
    for (int i = 0; i < 4; ++i)
#pragma unroll
        for (int j = 0; j < 4; ++j)
            acc[i][j] = (v4f){0.f, 0.f, 0.f, 0.f};

    for (int kt = 0; kt < KDIM / 32; ++kt) {
#pragma unroll
        for (int p = 0; p < 2; ++p) {
            int cb  = w * 128 + p * 64;
            int c   = cb + lane;
            int row = c >> 2;
            int cc  = (c & 3) ^ ((c >> 3) & 3);
            const unsigned short* sa = A + (size_t)(m0 + row) * KDIM + kt * 32 + cc * 8;
            GLD16(&As[cb * 8], sa);
            const unsigned short* sb = B + (size_t)(n0 + row) * KDIM + kt * 32 + cc * 8;
            GLD16(&Bs[cb * 8], sb);
        }
        __syncthreads();

        v8s af[4], bf[4];
#pragma unroll
        for (int mt = 0; mt < 4; ++mt)
            af[mt] = *(const v8s*)&As[(wm * 64 + mt * 16 + l16) * 32 + swz * 8];
#pragma unroll
        for (int nt = 0; nt < 4; ++nt)
            bf[nt] = *(const v8s*)&Bs[(wn * 64 + nt * 16 + l16) * 32 + swz * 8];
#pragma unroll
        for (int mt = 0; mt < 4; ++mt)
#pragma unroll
            for (int nt = 0; nt < 4; ++nt)
                acc[mt][nt] = __builtin_amdgcn_mfma_f32_16x16x32_bf16(af[mt], bf[nt], acc[mt][nt], 0, 0, 0);
        __syncthreads();
    }

    const int h  = m0 >> 10;          // head (uniform per block)
    const int d0 = (m0 >> 4) & 63;    // first of this block's 8 d values
    float4 bias4[4];
#pragma unroll
    for (int mt = 0; mt < 4; ++mt)
        bias4[mt] = *(const float4*)&bias[m0 + wm * 64 + mt * 16 + quad * 4];
#pragma unroll
    for (int nt = 0; nt < 4; ++nt) {
        int token = n0 + wn * 64 + nt * 16 + l16;
        float4 av = *(const float4*)&attn[(size_t)token * (HNUM * RNUM) + h * RNUM + quad * 4];
#pragma unroll
        for (int mt = 0; mt < 4; ++mt) {
            v4f a = acc[mt][nt];
            float val = (a[0] + bias4[mt].x) * av.x
                      + (a[1] + bias4[mt].y) * av.y
                      + (a[2] + bias4[mt].z) * av.z
                      + (a[3] + bias4[mt].w) * av.w;
            val += __shfl_xor(val, 16);
            val += __shfl_xor(val, 32);
            if (quad == 0)
                Os[(wn * 64 + nt * 16 + l16) * 8 + (wm * 4 + mt)] = f2b(val * 0.125f);
        }
    }
    __syncthreads();
    if (tid < 128) {
        int sg = n0 + tid;            // global token
        int g  = (sg >> 11) * 2048 + h * 256 + ((sg & 2047) >> 3);
        int j  = (sg & 7) * 64 + d0;
        *(v8s*)&outH[(size_t)g * EDIM + j] = *(const v8s*)&Os[tid * 8];
    }
}

// per (token, head): z_r = -0.5*mean_d(((q-k)/w)^2), softmax over 16 rules.
// grid (TOKENS/16, HNUM), block 256 = 16 tokens x 16 rules.
#define RST 72   // padded LDS row stride (floats)
__global__ __launch_bounds__(256)
void rules_softmax(const unsigned short* __restrict__ q,  // bf16 (8192 x 512)
                   const float* __restrict__ rk,
                   const float* __restrict__ rw,
                   float* __restrict__ attn)
{
    __shared__ float ql[16 * RST];
    __shared__ float rkl[16 * RST];
    __shared__ float iwl[16 * RST];
    const int h   = blockIdx.y;
    const int t0  = blockIdx.x * 16;
    const int tid = threadIdx.x;

#pragma unroll
    for (int i = 0; i < 4; ++i) {
        int jj = tid + i * 256;
        int r = jj >> 6, d = jj & 63;
        rkl[r * RST + d] = rk[h * (RNUM * DDIM) + jj];
        float wv = rw[h * (RNUM * DDIM) + jj];
        iwl[r * RST + d] = 1.0f / (wv * wv);
    }
    {
        int jj = tid * 4;
        int row = jj >> 6, d = jj & 63;
        const unsigned short* src = q + (size_t)(t0 + row) * EDIM + h * DDIM + d;
        unsigned short u0 = src[0], u1 = src[1], u2 = src[2], u3 = src[3];
        ql[row * RST + d + 0] = b2f(u0);
        ql[row * RST + d + 1] = b2f(u1);
        ql[row * RST + d + 2] = b2f(u2);
        ql[row * RST + d + 3] = b2f(u3);
    }
    __syncthreads();

    const int tl = tid >> 4;
    const int r  = tid & 15;
    const float* qrow = &ql[tl * RST];
    const float* krow = &rkl[r * RST];
    const float* wrow = &iwl[r * RST];
    float z = 0.f;
#pragma unroll
    for (int d4 = 0; d4 < 16; ++d4) {
        float4 qv = *(const float4*)&qrow[d4 * 4];
        float4 kv = *(const float4*)&krow[d4 * 4];
        float4 wv = *(const float4*)&wrow[d4 * 4];
        float a0 = qv.x - kv.x; z += a0 * a0 * wv.x;
        float a1 = qv.y - kv.y; z += a1 * a1 * wv.y;
        float a2 = qv.z - kv.z; z += a2 * a2 * wv.z;
        float a3 = qv.w - kv.w; z += a3 * a3 * wv.w;
    }
    z *= (-0.5f / 64.f);
    float mx = z;
#pragma unroll
    for (int s = 1; s < 16; s <<= 1) mx = fmaxf(mx, __shfl_xor(mx, s));
    float e = __expf(z - mx);
    float sum = e;
#pragma unroll
    for (int s = 1; s < 16; s <<= 1) sum += __shfl_xor(sum, s);
    attn[(size_t)(t0 + tl) * (HNUM * RNUM) + h * RNUM + r] = e / sum;
}

extern "C" void kernel_launch(void* const* d_in, const int* in_sizes, int n_in,
                              void* d_out, int out_size, void* d_ws, size_t ws_size,
                              hipStream_t stream) {
    const float* query = (const float*)d_in[0];
    // d_in[1] = key (unused by the reference)
    const float* value = (const float*)d_in[2];
    const float* Wq = (const float*)d_in[3];
    const float* bq = (const float*)d_in[4];
    const float* Wv = (const float*)d_in[5];
    const float* bv = (const float*)d_in[6];
    const float* Wo = (const float*)d_in[7];
    const float* bo = (const float*)d_in[8];
    const float* rk = (const float*)d_in[9];
    const float* rw = (const float*)d_in[10];

    char* ws = (char*)d_ws;
    unsigned short* qbf  = (unsigned short*)(ws);                       //  8 MiB: query bf16
    unsigned short* vbf  = (unsigned short*)(ws + (size_t)( 8 << 20));  //  8 MiB: value bf16
    unsigned short* Wqb  = (unsigned short*)(ws + (size_t)(16 << 20));  // 0.5 MiB
    unsigned short* Wvb  = (unsigned short*)(ws + (size_t)(17 << 20));  //  8 MiB
    unsigned short* Wob  = (unsigned short*)(ws + (size_t)(25 << 20));  // 0.5 MiB
    unsigned short* out1 = (unsigned short*)(ws + (size_t)(26 << 20));  //  8 MiB: scrambled bf16
    unsigned short* qf   = (unsigned short*)(ws + (size_t)(34 << 20));  //  8 MiB: q bf16
    float* attn          = (float*)(ws + (size_t)(42 << 20));           //  4 MiB: attn fp32

    dim3 blk(256);
    // 0) fp32 -> bf16 conversions
    cvt5<<<dim3(2048, 5), blk, 0, stream>>>(query, value, Wv, Wq, Wo,
                                            qbf, vbf, Wvb, Wqb, Wob,
                                            TOKENS * EDIM, TOKENS * EDIM, EDIM * RNUM * EDIM,
                                            EDIM * EDIM, EDIM * EDIM);
    // 1) q = bf16((query @ Wq^T + bq) * D^-0.5)   [64x64 tiles, 1024 blocks]
    gemm64<0><<<dim3(TOKENS / 64, EDIM / 64), blk, 0, stream>>>(qbf, Wqb, bq, nullptr, qf);
    // 2) fuzzy rule attention weights
    rules_softmax<<<dim3(TOKENS / 16, HNUM), blk, 0, stream>>>(qf, rk, rw, attn);
    // 3) transposed V-GEMM (BK=32, swizzled) + rule contraction -> scrambled out1
    gemm_v<<<dim3((EDIM * RNUM) / 128, TOKENS / 128), blk, 0, stream>>>(Wvb, vbf, bv, out1, attn);
    // 4) final projection -> d_out (fp32)  [64x64 tiles, 1024 blocks]
    gemm64<2><<<dim3(TOKENS / 64, EDIM / 64), blk, 0, stream>>>(out1, Wob, bo, (float*)d_out, nullptr);
}